// Round 13
// baseline (8368.217 us; speedup 1.0000x reference)
//
#include <hip/hip_runtime.h>
#include <math.h>

#define TT 2048
#define BB 64
#define II 64
#define HH 512
#define OO 32
#define OCC 8
#define QS 128   // k/h slice per WG (4-way split)
#define WT_LD 48 // padded leading dim of packed readout weights

// d_out layout: output [T,B,32] | output_ctx [T,B,8] | rate_all [T,B,512]
#define OUT1_OFF ((size_t)TT * BB * OO)
#define RATE_OFF (OUT1_OFF + (size_t)TT * BB * OCC)

// d_ws: P2[B][4 writer][3 slot][2 par][64] u64 (1.5MB) | flags @1.5MB | Wt @2MB
// band slot: writer p publishes to target (p+j)&3 in slot j-1; the band packs
// h = 128*target + i (lo32) and h + 64 (hi32) into word i.
#define P2_IDX(b,p,slot,par) ((((((size_t)(b) * 4 + (p)) * 3 + (slot)) * 2 + (par)) * 64))
#define FLAG_BYTE_OFF ((size_t)0x180000)
#define FLAG_IDX(b,p,slot) ((((b) * 4 + (p)) * 3 + (slot)) * 16)
#define FLAG_BYTES (BB * 4 * 3 * 16 * sizeof(int))
#define WT_BYTE_OFF ((size_t)2 << 20)

// ---------------------------------------------------------------------------
// Pack Wt[h][o] = Wo[o][h] / Woc[o-32][h] / pad  (coalesced readout weights)
// ---------------------------------------------------------------------------
__global__ __launch_bounds__(256) void pack_wt(
    const float* __restrict__ Wo, const float* __restrict__ Woc,
    float* __restrict__ Wt)
{
    int idx = blockIdx.x * 256 + threadIdx.x;
    if (idx >= HH * WT_LD) return;
    int h = idx / WT_LD, o = idx % WT_LD;
    float v = 0.f;
    if (o < OO)            v = Wo[(size_t)o * HH + h];
    else if (o < OO + OCC) v = Woc[(size_t)(o - OO) * HH + h];
    Wt[idx] = v;
}

// ---------------------------------------------------------------------------
// Recurrent scan, 4-way k-split, fused prefold, WAVE-SPECIALIZED sync:
//   waves 0-7  : dot + (inband waves 2q,2q+1: consumer role)
//   waves 8-10 : dot + publisher for peer band j=wv-7 (reduce from parts,
//                u64-pack, store, WAVE-LOCAL vmcnt(0), flag)  -- no block B2
//   waves 11-13: dot + poller (1 lane) for peer band flags
//   waves 14-15: dot only
// Barriers: B1 (parts ready) / B3 (peer flags seen) / B4 (st updated).
// SYNC RULES (hard-won): r8: no store gated behind a poll, store/poll waves
// disjoint. r10: poll traffic O(3)/WG. r4: relaxed agent atomics only.
// FP order bit-identical to r12 (absmax must stay exactly 0.125).
// ---------------------------------------------------------------------------
__global__ __launch_bounds__(1024) void rnn_scan13(
    const float* __restrict__ x,       // [T,B,I]
    const float* __restrict__ rate0,   // [B,H]
    const float* __restrict__ noise,   // [T,B,H]
    const float* __restrict__ Wh,      // [H,H] row-major
    const float* __restrict__ Wi,      // [H,I]
    const float* __restrict__ bi,
    const float* __restrict__ bh,
    float* __restrict__ rate_out,      // [T,B,H]
    unsigned long long* P2,
    int* flags)
{
    __shared__ float  st[QS];          // own state slice
    __shared__ float  parts[8 * HH];   // per-g partials (16 KB)
    __shared__ float4 wi4[II / 4][QS]; // Wi slice, [c4][l]
    __shared__ float4 xbuf4[II / 4];   // x_t

    const int bid = blockIdx.x;
    const int q   = bid >> 6;          // quarter 0..3
    const int b   = bid & 63;          // batch
    const int tid = threadIdx.x;
    const int g   = tid >> 7;          // 0..7 -> 16 k-rows each
    const int ht  = tid & 127;
    const int h4  = 4 * ht;
    const int kq  = q * QS + g * 16;
    const int wv  = tid >> 6;          // wave id 0..15
    const int lane = tid & 63;

    const double SIG = 1.5 / sqrt(512.0);
    const float  NS  = (float)sqrt(2.0 * SIG * SIG / 0.1);

    // Wh weights fully register-resident: wreg[m] = W^T[kq+m][h4..h4+3]
    float4 wreg[16];
    #pragma unroll
    for (int m = 0; m < 16; ++m) {
        wreg[m].x = Wh[(size_t)(h4 + 0) * HH + kq + m];
        wreg[m].y = Wh[(size_t)(h4 + 1) * HH + kq + m];
        wreg[m].z = Wh[(size_t)(h4 + 2) * HH + kq + m];
        wreg[m].w = Wh[(size_t)(h4 + 3) * HH + kq + m];
    }

    // Wi rows of own h-slice -> LDS (one-time)
    for (int i = tid; i < QS * (II / 4); i += 1024) {
        int l2 = i >> 4, c4 = i & 15;
        wi4[c4][l2] = *(const float4*)&Wi[(size_t)(q * QS + l2) * II + 4 * c4];
    }

    const bool inband = (tid >= q * QS) && (tid < q * QS + QS);
    const int  l      = tid - q * QS;  // local h index when inband
    float rf = 0.f, bsum = 0.f;
    if (inband) {
        rf   = rate0[b * HH + tid];
        bsum = bi[tid] + bh[tid];
    }
    if (tid < QS) st[tid] = rate0[b * HH + q * QS + tid];
    __syncthreads();

    for (int t = 0; t < TT; ++t) {
        const int par = t & 1;
        const size_t row = ((size_t)t * BB + b) * HH;

        // stage x_t (written pre-B1, read post-B1 in prefold)
        if (tid < II / 4)
            xbuf4[tid] = *(const float4*)&x[((size_t)t * BB + b) * II + 4 * tid];

        // ---- dot: all threads; 4 h-cols over 16 k-rows (st wave-broadcast)
        float a0 = 0.f, a1 = 0.f, a2 = 0.f, a3 = 0.f;
        #pragma unroll
        for (int mm = 0; mm < 4; ++mm) {
            float4 s4 = *(const float4*)&st[g * 16 + 4 * mm];
            a0 += wreg[4*mm].x*s4.x + wreg[4*mm+1].x*s4.y + wreg[4*mm+2].x*s4.z + wreg[4*mm+3].x*s4.w;
            a1 += wreg[4*mm].y*s4.x + wreg[4*mm+1].y*s4.y + wreg[4*mm+2].y*s4.z + wreg[4*mm+3].y*s4.w;
            a2 += wreg[4*mm].z*s4.x + wreg[4*mm+1].z*s4.y + wreg[4*mm+2].z*s4.z + wreg[4*mm+3].z*s4.w;
            a3 += wreg[4*mm].w*s4.x + wreg[4*mm+1].w*s4.y + wreg[4*mm+2].w*s4.z + wreg[4*mm+3].w*s4.w;
        }
        *(float4*)&parts[g * HH + h4] = make_float4(a0, a1, a2, a3);
        __syncthreads();                      // B1: parts + xbuf ready

        float s = 0.f, pre = 0.f;
        if (inband) {
            // noise issued AFTER B1: latency hides under prefold+poll window
            float nz = noise[row + tid];
            #pragma unroll
            for (int p = 0; p < 8; ++p) s += parts[p * HH + tid];
            pre = bsum + NS * nz;
            #pragma unroll
            for (int c4 = 0; c4 < II / 4; ++c4) {
                float4 wv4 = wi4[c4][l];
                float4 xv  = xbuf4[c4];
                pre += wv4.x * xv.x + wv4.y * xv.y + wv4.z * xv.z + wv4.w * xv.w;
            }
        } else if (wv >= 8 && wv < 11) {
            // ---- publisher: band j -> peer pj; pack (h, h+64) into u64
            const int j  = wv - 7;            // 1..3
            const int pj = (q + j) & 3;
            const int hb = pj * QS + lane;
            float slo = 0.f, shi = 0.f;
            #pragma unroll
            for (int p = 0; p < 8; ++p) {
                slo += parts[p * HH + hb];
                shi += parts[p * HH + hb + 64];
            }
            unsigned long long w =
                ((unsigned long long)__float_as_uint(shi) << 32) | __float_as_uint(slo);
            __hip_atomic_store(&P2[P2_IDX(b, q, j - 1, par) + lane], w,
                               __ATOMIC_RELAXED, __HIP_MEMORY_SCOPE_AGENT);
            asm volatile("s_waitcnt vmcnt(0)" ::: "memory");   // wave-local drain
            if (lane == 0)
                __hip_atomic_store(&flags[FLAG_IDX(b, q, j - 1)], t + 1,
                                   __ATOMIC_RELAXED, __HIP_MEMORY_SCOPE_AGENT);
        } else if (wv >= 11 && wv < 14) {
            // ---- poller: peer pj's band targeted at q lives in slot 3-j
            if (lane == 0) {
                const int j  = wv - 10;       // 1..3
                const int pj = (q + j) & 3;
                int* f = &flags[FLAG_IDX(b, pj, 3 - j)];
                while (__hip_atomic_load(f, __ATOMIC_RELAXED,
                                         __HIP_MEMORY_SCOPE_AGENT) < t + 1) {}
            }
        }
        __syncthreads();                      // B3: peers' bands published

        // ---- consume: own-slice update
        if (inband) {
            float tot = pre + s;
            #pragma unroll
            for (int j = 1; j < 4; ++j) {
                const int pj = (q + j) & 3;
                unsigned long long u = __hip_atomic_load(
                    &P2[P2_IDX(b, pj, 3 - j, par) + (l & 63)],
                    __ATOMIC_RELAXED, __HIP_MEMORY_SCOPE_AGENT);
                unsigned bits = (l >> 6) ? (unsigned)(u >> 32) : (unsigned)u;
                tot += __uint_as_float(bits);
            }
            rf = 0.9f * rf + 0.1f * tanhf(tot);
            rate_out[row + tid] = rf;
            st[l] = rf;
        }
        __syncthreads();                      // B4: st ready for next dot
    }
}

// ---------------------------------------------------------------------------
// Readout with transposed weights (r12, proven ~0.2 ms).
// ---------------------------------------------------------------------------
__global__ __launch_bounds__(512) void readout2(
    const float* __restrict__ rate_all,
    const float* __restrict__ Wt,   // [512][48] packed [Wo | Woc | pad]
    const float* __restrict__ bo, const float* __restrict__ boc,
    float* __restrict__ out, float* __restrict__ outc)
{
    __shared__ float rbuf[16][HH];
    const int tid  = threadIdx.x;
    const size_t row0 = (size_t)blockIdx.x * 16;

    for (int i = tid; i < 16 * (HH / 4); i += 512) {
        int r = i >> 7, c = (i & 127) * 4;
        *(float4*)&rbuf[r][c] = *(const float4*)&rate_all[(row0 + r) * HH + c];
    }
    __syncthreads();

    {
        const int r = tid >> 5, o = tid & 31;
        const float* wt = Wt + o;
        float acc = 0.f;
        #pragma unroll 8
        for (int h = 0; h < HH; h += 4) {
            float4 rv = *(const float4*)&rbuf[r][h];
            acc += rv.x * wt[(size_t)(h + 0) * WT_LD]
                 + rv.y * wt[(size_t)(h + 1) * WT_LD]
                 + rv.z * wt[(size_t)(h + 2) * WT_LD]
                 + rv.w * wt[(size_t)(h + 3) * WT_LD];
        }
        out[(row0 + r) * OO + o] = acc + bo[o];
    }
    if (tid < 128) {
        const int r = tid >> 3, c = tid & 7;
        const float* wt = Wt + OO + c;
        float acc = 0.f;
        #pragma unroll 8
        for (int h = 0; h < HH; h += 4) {
            float4 rv = *(const float4*)&rbuf[r][h];
            acc += rv.x * wt[(size_t)(h + 0) * WT_LD]
                 + rv.y * wt[(size_t)(h + 1) * WT_LD]
                 + rv.z * wt[(size_t)(h + 2) * WT_LD]
                 + rv.w * wt[(size_t)(h + 3) * WT_LD];
        }
        outc[(row0 + r) * OCC + c] = acc + boc[c];
    }
}

// ---------------------------------------------------------------------------
extern "C" void kernel_launch(void* const* d_in, const int* in_sizes, int n_in,
                              void* d_out, int out_size, void* d_ws, size_t ws_size,
                              hipStream_t stream)
{
    const float* x     = (const float*)d_in[0];
    const float* rate0 = (const float*)d_in[1];
    const float* noise = (const float*)d_in[2];
    const float* Wi    = (const float*)d_in[3];
    const float* bi    = (const float*)d_in[4];
    const float* Wh    = (const float*)d_in[5];
    const float* bh    = (const float*)d_in[6];
    const float* Wo    = (const float*)d_in[7];
    const float* bo    = (const float*)d_in[8];
    const float* Woc   = (const float*)d_in[9];
    const float* boc   = (const float*)d_in[10];

    float* out   = (float*)d_out;
    float* rateb = out + RATE_OFF;
    unsigned long long* P2 = (unsigned long long*)d_ws;
    int*   flags = (int*)((char*)d_ws + FLAG_BYTE_OFF);
    float* Wt    = (float*)((char*)d_ws + WT_BYTE_OFF);

    hipMemsetAsync(flags, 0, FLAG_BYTES, stream);   // ws is not re-poisoned
    pack_wt<<<(HH * WT_LD + 255) / 256, 256, 0, stream>>>(Wo, Woc, Wt);
    rnn_scan13<<<4 * BB, 1024, 0, stream>>>(x, rate0, noise, Wh, Wi, bi, bh,
                                            rateb, P2, flags);
    readout2<<<TT * BB / 16, 512, 0, stream>>>(rateb, Wt, bo, boc,
                                               out, out + OUT1_OFF);
}

// Round 14
// 5131.116 us; speedup vs baseline: 1.6309x; 1.6309x over previous
//
#include <hip/hip_runtime.h>
#include <math.h>

#define TT 2048
#define BB 64
#define II 64
#define HH 512
#define OO 32
#define OCC 8
#define QS 128   // k/h slice per WG (4-way split)
#define WT_LD 48 // padded leading dim of packed readout weights

// d_out layout: output [T,B,32] | output_ctx [T,B,8] | rate_all [T,B,512]
#define OUT1_OFF ((size_t)TT * BB * OO)
#define RATE_OFF (OUT1_OFF + (size_t)TT * BB * OCC)

// d_ws layout: P[B][4][2][HH] floats (1 MB) | flags @1MB (16KB) | Wt @2MB (96KB)
#define FLAG_BYTE_OFF ((size_t)1 << 20)
#define FLAG_BYTES (BB * 4 * 16 * sizeof(int))
#define WT_BYTE_OFF ((size_t)2 << 20)

// Barrier WITHOUT vmcnt drain: LDS visibility only. Safe here because (a) the
// publish protocol has its own scoped vmcnt drain (below), (b) consume loads
// complete via data dependence before their values reach st/lgkm, (c)
// rate_out stores are fire-and-forget across steps.
#define BAR_LGKM() asm volatile("s_waitcnt lgkmcnt(0)\n\ts_barrier" ::: "memory")

// ---------------------------------------------------------------------------
// Pack Wt[h][o] = Wo[o][h] / Woc[o-32][h] / pad  (coalesced readout weights)
// ---------------------------------------------------------------------------
__global__ __launch_bounds__(256) void pack_wt(
    const float* __restrict__ Wo, const float* __restrict__ Woc,
    float* __restrict__ Wt)
{
    int idx = blockIdx.x * 256 + threadIdx.x;
    if (idx >= HH * WT_LD) return;
    int h = idx / WT_LD, o = idx % WT_LD;
    float v = 0.f;
    if (o < OO)            v = Wo[(size_t)o * HH + h];
    else if (o < OO + OCC) v = Woc[(size_t)(o - OO) * HH + h];
    Wt[idx] = v;
}

// ---------------------------------------------------------------------------
// Recurrent scan = r12 structure (proven 4.56 ms) with barrier-drain surgery:
//  - All 4 barriers are lgkmcnt-only (BAR_LGKM): prev rate_out stores, x
//    staging loads, and noise loads no longer serialize the step.
//  - Protocol drain kept, scoped: storing waves ({0..7} minus the 2 inband
//    waves) execute s_waitcnt vmcnt(0) before B2 -> P stores IF-acked before
//    the flag store. Inband waves' noise loads no longer gate the flag.
//  - x double-buffered in registers: load x(t+2) after B3; ds_write x(t+1)
//    from regs at the next B3 (wave 0's load wait leaves B1's path).
// SYNC RULES (hard-won): r8: no store gated behind a poll; store (tid 0,
// wave 0) and pollers (waves 1-3) disjoint. r10: poll traffic O(3)/WG.
// r4: relaxed agent atomics only (no cache maintenance).
// r13: no wave-specialized publishers -- parallel reduce + single flag wins.
// FP order bit-identical to r12 (absmax tripwire: expect exactly 0.125).
// ---------------------------------------------------------------------------
__global__ __launch_bounds__(1024) void rnn_scan14(
    const float* __restrict__ x,       // [T,B,I]
    const float* __restrict__ rate0,   // [B,H]
    const float* __restrict__ noise,   // [T,B,H]
    const float* __restrict__ Wh,      // [H,H] row-major
    const float* __restrict__ Wi,      // [H,I]
    const float* __restrict__ bi,
    const float* __restrict__ bh,
    float* __restrict__ rate_out,      // [T,B,H]
    float* P,                          // [B][4][2][HH]
    int* flags)                        // [B*4*16]
{
    __shared__ float  st[QS];          // own state slice
    __shared__ float  parts[8 * HH];   // per-g partials (16 KB)
    __shared__ float4 wi4[II / 4][QS]; // Wi slice, [c4][l]
    __shared__ float4 xbuf4[II / 4];   // x_t

    const int bid = blockIdx.x;
    const int q   = bid >> 6;          // quarter 0..3
    const int b   = bid & 63;          // batch
    const int tid = threadIdx.x;
    const int g   = tid >> 7;          // 0..7 -> 16 k-rows each
    const int ht  = tid & 127;
    const int h4  = 4 * ht;
    const int kq  = q * QS + g * 16;
    const int wv  = tid >> 6;          // wave id

    const double SIG = 1.5 / sqrt(512.0);
    const float  NS  = (float)sqrt(2.0 * SIG * SIG / 0.1);

    // Wh weights fully register-resident: wreg[m] = W^T[kq+m][h4..h4+3]
    float4 wreg[16];
    #pragma unroll
    for (int m = 0; m < 16; ++m) {
        wreg[m].x = Wh[(size_t)(h4 + 0) * HH + kq + m];
        wreg[m].y = Wh[(size_t)(h4 + 1) * HH + kq + m];
        wreg[m].z = Wh[(size_t)(h4 + 2) * HH + kq + m];
        wreg[m].w = Wh[(size_t)(h4 + 3) * HH + kq + m];
    }

    // Wi rows of own h-slice -> LDS (one-time)
    for (int i = tid; i < QS * (II / 4); i += 1024) {
        int l2 = i >> 4, c4 = i & 15;
        wi4[c4][l2] = *(const float4*)&Wi[(size_t)(q * QS + l2) * II + 4 * c4];
    }

    const bool inband = (tid >= q * QS) && (tid < q * QS + QS);
    const bool storer = (wv < 8) && ((wv >> 1) != q);   // wave-uniform
    const int  l      = tid - q * QS;  // local h index when inband
    float rf = 0.f, bsum = 0.f;
    if (inband) {
        rf   = rate0[b * HH + tid];
        bsum = bi[tid] + bh[tid];
    }
    if (tid < QS) st[tid] = rate0[b * HH + q * QS + tid];
    int* myflag = &flags[(b * 4 + q) * 16];

    // x double-buffer: xbuf4 = x(0); xreg = x(1)
    float4 xreg = make_float4(0.f, 0.f, 0.f, 0.f);
    if (tid < II / 4) {
        xbuf4[tid] = *(const float4*)&x[(size_t)b * II + 4 * tid];
        if (TT > 1)
            xreg = *(const float4*)&x[((size_t)BB + b) * II + 4 * tid];
    }
    __syncthreads();   // prologue: full barrier once is fine

    for (int t = 0; t < TT; ++t) {
        const int par = t & 1;
        const size_t row = ((size_t)t * BB + b) * HH;

        float nz = 0.f;
        if (inband) nz = noise[row + tid];    // early; consumed post-flag

        // ---- dot: 4 h-cols over 16 k-rows (st wave-broadcast)
        float a0 = 0.f, a1 = 0.f, a2 = 0.f, a3 = 0.f;
        #pragma unroll
        for (int mm = 0; mm < 4; ++mm) {
            float4 s4 = *(const float4*)&st[g * 16 + 4 * mm];
            a0 += wreg[4*mm].x*s4.x + wreg[4*mm+1].x*s4.y + wreg[4*mm+2].x*s4.z + wreg[4*mm+3].x*s4.w;
            a1 += wreg[4*mm].y*s4.x + wreg[4*mm+1].y*s4.y + wreg[4*mm+2].y*s4.z + wreg[4*mm+3].y*s4.w;
            a2 += wreg[4*mm].z*s4.x + wreg[4*mm+1].z*s4.y + wreg[4*mm+2].z*s4.z + wreg[4*mm+3].z*s4.w;
            a3 += wreg[4*mm].w*s4.x + wreg[4*mm+1].w*s4.y + wreg[4*mm+2].w*s4.z + wreg[4*mm+3].w*s4.w;
        }
        *(float4*)&parts[g * HH + h4] = make_float4(a0, a1, a2, a3);
        BAR_LGKM();                           // B1: parts ready (LDS only)

        // ---- reduce over g; publish peer bands to IF (own band kept local)
        float s = 0.f;
        if (tid < HH) {
            #pragma unroll
            for (int p = 0; p < 8; ++p) s += parts[p * HH + tid];
            if (!inband)
                __hip_atomic_store(&P[(((size_t)b * 4 + q) * 2 + par) * HH + tid], s,
                                   __ATOMIC_RELAXED, __HIP_MEMORY_SCOPE_AGENT);
        }
        if (storer)                            // protocol drain, storing waves only
            asm volatile("s_waitcnt vmcnt(0)" ::: "memory");
        BAR_LGKM();                           // B2: stores drained (by storers)

        // ---- flag publish (wave 0, immediately after B2)
        if (tid == 0)
            __hip_atomic_store(myflag, t + 1, __ATOMIC_RELAXED,
                               __HIP_MEMORY_SCOPE_AGENT);

        // ---- fused prefold: hides under the poll window
        float pre = 0.f;
        if (inband) {
            pre = bsum + NS * nz;
            #pragma unroll
            for (int c4 = 0; c4 < II / 4; ++c4) {
                float4 wv4 = wi4[c4][l];
                float4 xv  = xbuf4[c4];
                pre += wv4.x * xv.x + wv4.y * xv.y + wv4.z * xv.z + wv4.w * xv.w;
            }
        }

        // ---- peer polls (waves 1..3; store above precedes polls -- r8 rule)
        if (tid == 64 || tid == 128 || tid == 192) {
            int* f = &flags[(b * 4 + ((q + (tid >> 6)) & 3)) * 16];
            while (__hip_atomic_load(f, __ATOMIC_RELAXED,
                                     __HIP_MEMORY_SCOPE_AGENT) < t + 1) {}
        }
        BAR_LGKM();                           // B3: peers' P published

        // ---- x double-buffer rotate (wave 0; load wait off B1's path)
        if (tid < II / 4) {
            xbuf4[tid] = xreg;                // x(t+1) into LDS
            if (t + 2 < TT)
                xreg = *(const float4*)&x[((size_t)(t + 2) * BB + b) * II + 4 * tid];
        }

        // ---- consume: own-slice update (consumer reuses its own s)
        if (inband) {
            float tot = pre + s;
            #pragma unroll
            for (int j = 1; j < 4; ++j) {
                const int pj = (q + j) & 3;
                tot += __hip_atomic_load(
                    &P[(((size_t)b * 4 + pj) * 2 + par) * HH + tid],
                    __ATOMIC_RELAXED, __HIP_MEMORY_SCOPE_AGENT);
            }
            rf = 0.9f * rf + 0.1f * tanhf(tot);
            rate_out[row + tid] = rf;         // fire-and-forget (never drained)
            st[l] = rf;
        }
        BAR_LGKM();                           // B4: st ready for next dot
    }
}

// ---------------------------------------------------------------------------
// Readout with transposed weights (r12, proven ~0.2 ms).
// ---------------------------------------------------------------------------
__global__ __launch_bounds__(512) void readout2(
    const float* __restrict__ rate_all,
    const float* __restrict__ Wt,   // [512][48] packed [Wo | Woc | pad]
    const float* __restrict__ bo, const float* __restrict__ boc,
    float* __restrict__ out, float* __restrict__ outc)
{
    __shared__ float rbuf[16][HH];
    const int tid  = threadIdx.x;
    const size_t row0 = (size_t)blockIdx.x * 16;

    for (int i = tid; i < 16 * (HH / 4); i += 512) {
        int r = i >> 7, c = (i & 127) * 4;
        *(float4*)&rbuf[r][c] = *(const float4*)&rate_all[(row0 + r) * HH + c];
    }
    __syncthreads();

    {
        const int r = tid >> 5, o = tid & 31;
        const float* wt = Wt + o;
        float acc = 0.f;
        #pragma unroll 8
        for (int h = 0; h < HH; h += 4) {
            float4 rv = *(const float4*)&rbuf[r][h];
            acc += rv.x * wt[(size_t)(h + 0) * WT_LD]
                 + rv.y * wt[(size_t)(h + 1) * WT_LD]
                 + rv.z * wt[(size_t)(h + 2) * WT_LD]
                 + rv.w * wt[(size_t)(h + 3) * WT_LD];
        }
        out[(row0 + r) * OO + o] = acc + bo[o];
    }
    if (tid < 128) {
        const int r = tid >> 3, c = tid & 7;
        const float* wt = Wt + OO + c;
        float acc = 0.f;
        #pragma unroll 8
        for (int h = 0; h < HH; h += 4) {
            float4 rv = *(const float4*)&rbuf[r][h];
            acc += rv.x * wt[(size_t)(h + 0) * WT_LD]
                 + rv.y * wt[(size_t)(h + 1) * WT_LD]
                 + rv.z * wt[(size_t)(h + 2) * WT_LD]
                 + rv.w * wt[(size_t)(h + 3) * WT_LD];
        }
        outc[(row0 + r) * OCC + c] = acc + boc[c];
    }
}

// ---------------------------------------------------------------------------
extern "C" void kernel_launch(void* const* d_in, const int* in_sizes, int n_in,
                              void* d_out, int out_size, void* d_ws, size_t ws_size,
                              hipStream_t stream)
{
    const float* x     = (const float*)d_in[0];
    const float* rate0 = (const float*)d_in[1];
    const float* noise = (const float*)d_in[2];
    const float* Wi    = (const float*)d_in[3];
    const float* bi    = (const float*)d_in[4];
    const float* Wh    = (const float*)d_in[5];
    const float* bh    = (const float*)d_in[6];
    const float* Wo    = (const float*)d_in[7];
    const float* bo    = (const float*)d_in[8];
    const float* Woc   = (const float*)d_in[9];
    const float* boc   = (const float*)d_in[10];

    float* out   = (float*)d_out;
    float* rateb = out + RATE_OFF;
    float* P     = (float*)d_ws;
    int*   flags = (int*)((char*)d_ws + FLAG_BYTE_OFF);
    float* Wt    = (float*)((char*)d_ws + WT_BYTE_OFF);

    hipMemsetAsync(flags, 0, FLAG_BYTES, stream);   // ws is not re-poisoned
    pack_wt<<<(HH * WT_LD + 255) / 256, 256, 0, stream>>>(Wo, Woc, Wt);
    rnn_scan14<<<4 * BB, 1024, 0, stream>>>(x, rate0, noise, Wh, Wi, bi, bh,
                                            rateb, P, flags);
    readout2<<<TT * BB / 16, 512, 0, stream>>>(rateb, Wt, bo, boc,
                                               out, out + OUT1_OFF);
}

// Round 15
// 4866.550 us; speedup vs baseline: 1.7195x; 1.0544x over previous
//
#include <hip/hip_runtime.h>
#include <math.h>

#define TT 2048
#define BB 64
#define II 64
#define HH 512
#define OO 32
#define OCC 8
#define QS 128   // k/h slice per WG (4-way split)
#define WT_LD 48 // padded leading dim of packed readout weights

// d_out layout: output [T,B,32] | output_ctx [T,B,8] | rate_all [T,B,512]
#define OUT1_OFF ((size_t)TT * BB * OO)
#define RATE_OFF (OUT1_OFF + (size_t)TT * BB * OCC)

// d_ws layout: P[B][4][2][HH] floats (1 MB) | flags @1MB (16KB) | Wt @2MB (96KB)
#define FLAG_BYTE_OFF ((size_t)1 << 20)
#define FLAG_BYTES (BB * 4 * 16 * sizeof(int))
#define WT_BYTE_OFF ((size_t)2 << 20)

// LDS-only barrier (no vmcnt drain). Used ONLY at B1/B4 where the sole vmem
// crossing is the fire-and-forget rate_out store (acked later, overlapped
// with the dot) -- the sync protocol's drain stays at B2's full syncthreads.
#define BAR_LGKM() asm volatile("s_waitcnt lgkmcnt(0)\n\ts_barrier" ::: "memory")

// ---------------------------------------------------------------------------
// Pack Wt[h][o] = Wo[o][h] / Woc[o-32][h] / pad  (coalesced readout weights)
// ---------------------------------------------------------------------------
__global__ __launch_bounds__(256) void pack_wt(
    const float* __restrict__ Wo, const float* __restrict__ Woc,
    float* __restrict__ Wt)
{
    int idx = blockIdx.x * 256 + threadIdx.x;
    if (idx >= HH * WT_LD) return;
    int h = idx / WT_LD, o = idx % WT_LD;
    float v = 0.f;
    if (o < OO)            v = Wo[(size_t)o * HH + h];
    else if (o < OO + OCC) v = Woc[(size_t)(o - OO) * HH + h];
    Wt[idx] = v;
}

// ---------------------------------------------------------------------------
// Recurrent scan = r12 (proven 4.56 ms) with exactly two lgkm-only barriers:
//   B1 (parts ready), B4 (st updated): LDS-only visibility needed; the only
//   vmem crossing them is the rate_out store whose ack now overlaps the dot.
//   B2 (full syncthreads): the protocol drain -- all P stores IF-acked in
//   every wave before tid 0's flag store (exactly as r12, proven).
//   B3 (full syncthreads): after poll detect (as r12).
// SYNC RULES (hard-won): r8: no store gated behind a poll; flag store
// (tid 0) and pollers (tids 64/128/192) in disjoint waves. r10: poll traffic
// O(3)/WG. r4: relaxed agent atomics only. r13/r14: no wave-specialized
// publishers, no all-lgkm barriers -- parallel reduce + single flag wins.
// ---------------------------------------------------------------------------
__global__ __launch_bounds__(1024) void rnn_scan15(
    const float* __restrict__ x,       // [T,B,I]
    const float* __restrict__ rate0,   // [B,H]
    const float* __restrict__ noise,   // [T,B,H]
    const float* __restrict__ Wh,      // [H,H] row-major
    const float* __restrict__ Wi,      // [H,I]
    const float* __restrict__ bi,
    const float* __restrict__ bh,
    float* __restrict__ rate_out,      // [T,B,H]
    float* P,                          // [B][4][2][HH]
    int* flags)                        // [B*4*16]
{
    __shared__ float  st[QS];          // own state slice
    __shared__ float  parts[8 * HH];   // per-g partials (16 KB)
    __shared__ float4 wi4[II / 4][QS]; // Wi slice, [c4][l]
    __shared__ float4 xbuf4[II / 4];   // x_t

    const int bid = blockIdx.x;
    const int q   = bid >> 6;          // quarter 0..3
    const int b   = bid & 63;          // batch
    const int tid = threadIdx.x;
    const int g   = tid >> 7;          // 0..7 -> 16 k-rows each
    const int ht  = tid & 127;
    const int h4  = 4 * ht;
    const int kq  = q * QS + g * 16;

    const double SIG = 1.5 / sqrt(512.0);
    const float  NS  = (float)sqrt(2.0 * SIG * SIG / 0.1);

    // Wh weights fully register-resident: wreg[m] = W^T[kq+m][h4..h4+3]
    float4 wreg[16];
    #pragma unroll
    for (int m = 0; m < 16; ++m) {
        wreg[m].x = Wh[(size_t)(h4 + 0) * HH + kq + m];
        wreg[m].y = Wh[(size_t)(h4 + 1) * HH + kq + m];
        wreg[m].z = Wh[(size_t)(h4 + 2) * HH + kq + m];
        wreg[m].w = Wh[(size_t)(h4 + 3) * HH + kq + m];
    }

    // Wi rows of own h-slice -> LDS (one-time)
    for (int i = tid; i < QS * (II / 4); i += 1024) {
        int l2 = i >> 4, c4 = i & 15;
        wi4[c4][l2] = *(const float4*)&Wi[(size_t)(q * QS + l2) * II + 4 * c4];
    }

    const bool inband = (tid >= q * QS) && (tid < q * QS + QS);
    const int  l      = tid - q * QS;  // local h index when inband
    float rf = 0.f, bsum = 0.f;
    if (inband) {
        rf   = rate0[b * HH + tid];
        bsum = bi[tid] + bh[tid];
    }
    if (tid < QS) st[tid] = rate0[b * HH + q * QS + tid];
    int* myflag = &flags[(b * 4 + q) * 16];
    __syncthreads();

    for (int t = 0; t < TT; ++t) {
        const int par = t & 1;
        const size_t row = ((size_t)t * BB + b) * HH;

        // stage x_t (read after B1 in prefold; next overwrite after B4)
        if (tid < II / 4)
            xbuf4[tid] = *(const float4*)&x[((size_t)t * BB + b) * II + 4 * tid];
        float nz = 0.f;
        if (inband) nz = noise[row + tid];    // early; consumed post-flag

        // ---- dot: this thread's 4 h-cols over its 16 k-rows (st broadcast)
        float a0 = 0.f, a1 = 0.f, a2 = 0.f, a3 = 0.f;
        #pragma unroll
        for (int mm = 0; mm < 4; ++mm) {
            float4 s4 = *(const float4*)&st[g * 16 + 4 * mm];
            a0 += wreg[4*mm].x*s4.x + wreg[4*mm+1].x*s4.y + wreg[4*mm+2].x*s4.z + wreg[4*mm+3].x*s4.w;
            a1 += wreg[4*mm].y*s4.x + wreg[4*mm+1].y*s4.y + wreg[4*mm+2].y*s4.z + wreg[4*mm+3].y*s4.w;
            a2 += wreg[4*mm].z*s4.x + wreg[4*mm+1].z*s4.y + wreg[4*mm+2].z*s4.z + wreg[4*mm+3].z*s4.w;
            a3 += wreg[4*mm].w*s4.x + wreg[4*mm+1].w*s4.y + wreg[4*mm+2].w*s4.z + wreg[4*mm+3].w*s4.w;
        }
        *(float4*)&parts[g * HH + h4] = make_float4(a0, a1, a2, a3);
        BAR_LGKM();                           // B1: parts+xbuf ready (LDS only)

        // ---- reduce over g; publish peer bands to IF (own band kept local)
        float s = 0.f;
        if (tid < HH) {
            #pragma unroll
            for (int p = 0; p < 8; ++p) s += parts[p * HH + tid];
            if (!inband)
                __hip_atomic_store(&P[(((size_t)b * 4 + q) * 2 + par) * HH + tid], s,
                                   __ATOMIC_RELAXED, __HIP_MEMORY_SCOPE_AGENT);
        }
        __syncthreads();                      // B2: full drain -> P at IF

        // ---- flag publish (wave 0, immediately after B2)
        if (tid == 0)
            __hip_atomic_store(myflag, t + 1, __ATOMIC_RELAXED,
                               __HIP_MEMORY_SCOPE_AGENT);

        // ---- fused prefold: hides under the poll window
        float pre = 0.f;
        if (inband) {
            pre = bsum + NS * nz;
            #pragma unroll
            for (int c4 = 0; c4 < II / 4; ++c4) {
                float4 wv4 = wi4[c4][l];
                float4 xv  = xbuf4[c4];
                pre += wv4.x * xv.x + wv4.y * xv.y + wv4.z * xv.z + wv4.w * xv.w;
            }
        }

        // ---- peer polls (waves 1..3; store above precedes polls -- r8 rule)
        if (tid == 64 || tid == 128 || tid == 192) {
            int* f = &flags[(b * 4 + ((q + (tid >> 6)) & 3)) * 16];
            while (__hip_atomic_load(f, __ATOMIC_RELAXED,
                                     __HIP_MEMORY_SCOPE_AGENT) < t + 1) {}
        }
        __syncthreads();                      // B3: peers' P published

        // ---- consume: own-slice update (consumer reuses its own s)
        if (inband) {
            float tot = pre + s;
            #pragma unroll
            for (int j = 1; j < 4; ++j) {
                const int pj = (q + j) & 3;
                tot += __hip_atomic_load(
                    &P[(((size_t)b * 4 + pj) * 2 + par) * HH + tid],
                    __ATOMIC_RELAXED, __HIP_MEMORY_SCOPE_AGENT);
            }
            rf = 0.9f * rf + 0.1f * tanhf(tot);
            rate_out[row + tid] = rf;         // fire-and-forget; ack overlaps dot
            st[l] = rf;
        }
        BAR_LGKM();                           // B4: st ready (LDS only)
    }
}

// ---------------------------------------------------------------------------
// Readout: 32 rows staged (64 KB LDS); thread (r=tid>>5, o=tid&31) computes
// rows r and r+16 -> each weight load amortized over 2 rows (halves the
// weight VMEM instruction count that dominated r12's readout).
// ---------------------------------------------------------------------------
__global__ __launch_bounds__(512) void readout3(
    const float* __restrict__ rate_all,
    const float* __restrict__ Wt,   // [512][48] packed [Wo | Woc | pad]
    const float* __restrict__ bo, const float* __restrict__ boc,
    float* __restrict__ out, float* __restrict__ outc)
{
    __shared__ float rbuf[32][HH];  // 64 KB
    const int tid  = threadIdx.x;
    const size_t row0 = (size_t)blockIdx.x * 32;

    for (int i = tid; i < 32 * (HH / 4); i += 512) {
        int r = i >> 7, c = (i & 127) * 4;
        *(float4*)&rbuf[r][c] = *(const float4*)&rate_all[(row0 + r) * HH + c];
    }
    __syncthreads();

    {
        const int r = tid >> 5, o = tid & 31;
        const float* wt = Wt + o;
        float acc0 = 0.f, acc1 = 0.f;
        #pragma unroll 8
        for (int h = 0; h < HH; ++h) {
            float w = wt[(size_t)h * WT_LD];
            acc0 += rbuf[r][h] * w;
            acc1 += rbuf[r + 16][h] * w;
        }
        out[(row0 + r) * OO + o]      = acc0 + bo[o];
        out[(row0 + r + 16) * OO + o] = acc1 + bo[o];
    }
    if (tid < 128) {
        const int r = tid >> 3, c = tid & 7;
        const float* wt = Wt + OO + c;
        float acc0 = 0.f, acc1 = 0.f;
        #pragma unroll 8
        for (int h = 0; h < HH; ++h) {
            float w = wt[(size_t)h * WT_LD];
            acc0 += rbuf[r][h] * w;
            acc1 += rbuf[r + 16][h] * w;
        }
        outc[(row0 + r) * OCC + c]      = acc0 + boc[c];
        outc[(row0 + r + 16) * OCC + c] = acc1 + boc[c];
    }
}

// ---------------------------------------------------------------------------
extern "C" void kernel_launch(void* const* d_in, const int* in_sizes, int n_in,
                              void* d_out, int out_size, void* d_ws, size_t ws_size,
                              hipStream_t stream)
{
    const float* x     = (const float*)d_in[0];
    const float* rate0 = (const float*)d_in[1];
    const float* noise = (const float*)d_in[2];
    const float* Wi    = (const float*)d_in[3];
    const float* bi    = (const float*)d_in[4];
    const float* Wh    = (const float*)d_in[5];
    const float* bh    = (const float*)d_in[6];
    const float* Wo    = (const float*)d_in[7];
    const float* bo    = (const float*)d_in[8];
    const float* Woc   = (const float*)d_in[9];
    const float* boc   = (const float*)d_in[10];

    float* out   = (float*)d_out;
    float* rateb = out + RATE_OFF;
    float* P     = (float*)d_ws;
    int*   flags = (int*)((char*)d_ws + FLAG_BYTE_OFF);
    float* Wt    = (float*)((char*)d_ws + WT_BYTE_OFF);

    hipMemsetAsync(flags, 0, FLAG_BYTES, stream);   // ws is not re-poisoned
    pack_wt<<<(HH * WT_LD + 255) / 256, 256, 0, stream>>>(Wo, Woc, Wt);
    rnn_scan15<<<4 * BB, 1024, 0, stream>>>(x, rate0, noise, Wh, Wi, bi, bh,
                                            rateb, P, flags);
    readout3<<<TT * BB / 32, 512, 0, stream>>>(rateb, Wt, bo, boc,
                                               out, out + OUT1_OFF);
}